// Round 18
// baseline (220.401 us; speedup 1.0000x reference)
//
#include <hip/hip_runtime.h>
#include <hip/hip_bf16.h>

#define NTOK 512
#define TJ 32
#define NTILE 16
#define EPSF 1e-5f

typedef __attribute__((ext_vector_type(4))) float f32x4;
typedef __attribute__((ext_vector_type(8))) short bf16x8;

struct HL { short hi; short lo; };

__device__ __forceinline__ short f2bf(float x) {
  __hip_bfloat16 h = __float2bfloat16(x);
  return *reinterpret_cast<short*>(&h);
}
__device__ __forceinline__ float bf2f(short s) {
  unsigned int u = ((unsigned int)(unsigned short)s) << 16;
  return __uint_as_float(u);
}
__device__ __forceinline__ HL splitbf(float x) {
  HL r; r.hi = f2bf(x); r.lo = f2bf(x - bf2f(r.hi)); return r;
}
__device__ __forceinline__ int pk(short a, short b) {
  return (int)(unsigned short)a | ((int)(unsigned short)b << 16);
}
__device__ __forceinline__ bf16x8 frag4(int d0, int d1, int d2, int d3) {
  union { int d[4]; bf16x8 v; } u;
  u.d[0] = d0; u.d[1] = d1; u.d[2] = d2; u.d[3] = d3;
  return u.v;
}

// Mono quadrant-per-wave kernel. 512 blocks (one per i), 256 threads = 4 waves.
// Wave q owns quadrant q: computes h-tiles 2q,2q+1 (phase A, H kept in regs),
// lhs rows of quadrant q in-lane, phase B via ds_bpermute'd B-frags. One
// barrier per tile. LDS: double-buffered staging + epilogue overlay (~19.7KB).
// Staging layout per buffer (floats), skew (j>>3)*4 for bank spread:
#define F0IDX(j,c) ((j)*16 + (((j)>>3)<<2) + (c))
#define F1IDX(j,c) ((j)*48 + (((j)>>3)<<2) + (c))
#define ST_F0   0
#define ST_F1   528
#define ST_RH   2080
#define ST_MK   2176
#define ST_SIZE 2208
#define OFF_BIASB 4224   // overlay: ACC [128][33] @0, biasb [128][4] @4224
#define OFF_EPI   4736   // m00/m10/p01/p11/raw/nrm
#define SMEM_FLOATS 4928

__global__ __launch_bounds__(256) void tfn_mono(
    const float* __restrict__ f0,  const float* __restrict__ f1,
    const float* __restrict__ rbf, const float* __restrict__ rhat,
    const int*  __restrict__ mask,
    const float* __restrict__ w00a, const float* __restrict__ b00a,
    const float* __restrict__ w00b, const float* __restrict__ b00b,
    const float* __restrict__ w10a, const float* __restrict__ b10a,
    const float* __restrict__ w10b, const float* __restrict__ b10b,
    const float* __restrict__ w01a, const float* __restrict__ b01a,
    const float* __restrict__ w01b, const float* __restrict__ b01b,
    const float* __restrict__ w11a, const float* __restrict__ b11a,
    const float* __restrict__ w11b, const float* __restrict__ b11b,
    const float* __restrict__ g0, const float* __restrict__ be0,
    const float* __restrict__ g1, const float* __restrict__ be1,
    float* __restrict__ out)
{
  __shared__ __align__(16) float smem[SMEM_FLOATS];
  float* ACCf  = smem;
  float* biasb = smem + OFF_BIASB;

  const int i = blockIdx.x;
  const int t = threadIdx.x;
  const int w = t >> 6;            // wave = quadrant
  const int lane = t & 63;
  const int col = lane & 15;
  const int quad = lane >> 4;
  const bool jlo = (quad < 2);     // needs jh=0 sources in bpermute

  const int base_mt = (w==0) ? 0 : (w==1) ? 1 : (w==2) ? 2 : 5;
  const int nmt     = (w < 2) ? 1 : 3;

  // bpermute source lanes (same col, quads 2q and 2q+1)
  const int srcA = ((((2*quad)  )&3)*16 + col) * 4;
  const int srcB = ((((2*quad)+1)&3)*16 + col) * 4;

  // q2 index precompute: mm = lmt*16+col -> f=mm/3, x=mm%3
  int fI[3], xI[3];
  #pragma unroll
  for (int lmt = 0; lmt < 3; ++lmt) { int mm = lmt*16 + col; fI[lmt] = mm/3; xI[lmt] = mm%3; }

  // ---- WA B-fragments (hi/lo) + ba for this wave's two h-tiles ----
  bf16x8 bw0h={0,0,0,0,0,0,0,0}, bw0l={0,0,0,0,0,0,0,0};
  bf16x8 bw1h={0,0,0,0,0,0,0,0}, bw1l={0,0,0,0,0,0,0,0};
  float ba0v, ba1v;
  {
    const int h0 = 32*w + col, h1 = 32*w + 16 + col;
    const float* r0 = (h0 < 32) ? (w00a + h0*16) : (h0 < 64) ? (w10a + (h0-32)*16)
                    : (h0 < 96) ? (w01a + (h0-64)*16) : (w11a + (h0-96)*16);
    const float* r1 = (h1 < 32) ? (w00a + h1*16) : (h1 < 64) ? (w10a + (h1-32)*16)
                    : (h1 < 96) ? (w01a + (h1-64)*16) : (w11a + (h1-96)*16);
    ba0v = (h0 < 32) ? b00a[h0] : (h0 < 64) ? b10a[h0-32] : (h0 < 96) ? b01a[h0-64] : b11a[h0-96];
    ba1v = (h1 < 32) ? b00a[h1] : (h1 < 64) ? b10a[h1-32] : (h1 < 96) ? b01a[h1-64] : b11a[h1-96];
    if (quad < 2) {
      #pragma unroll
      for (int e = 0; e < 8; ++e) {
        HL s0 = splitbf(r0[quad*8 + e]); bw0h[e] = s0.hi; bw0l[e] = s0.lo;
        HL s1 = splitbf(r1[quad*8 + e]); bw1h[e] = s1.hi; bw1l[e] = s1.lo;
      }
    }
  }

  // ---- prologue: load + stage tile 0; load rbf tile 0 ----
  float4 cr00, cr01, cr10, cr11;                  // current tile rbf frag rows
  {
    const int j0 = 0;
    if (t < 128) { const int jj = t>>2, e = t&3;
      *(float4*)&smem[ST_F0 + F0IDX(jj, e*4)] = *(const float4*)(f0 + (j0+jj)*16 + e*4); }
    { const int q = t, jj = q/12, e = q%12;
      if (q < 384) *(float4*)&smem[ST_F1 + F1IDX(jj, e*4)] = *(const float4*)(f1 + (j0+jj)*48 + e*4); }
    if (t < 128) { const int q = t+256, jj = q/12, e = q%12;
      *(float4*)&smem[ST_F1 + F1IDX(jj, e*4)] = *(const float4*)(f1 + (j0+jj)*48 + e*4); }
    if (t < 24) *(float4*)&smem[ST_RH + t*4] = *(const float4*)(rhat + ((size_t)i*NTOK + j0)*3 + t*4);
    if (t < 8) {
      int4 mv = *(const int4*)(mask + (size_t)i*NTOK + j0 + t*4);
      smem[ST_MK+t*4+0] = mv.x?1.f:0.f; smem[ST_MK+t*4+1] = mv.y?1.f:0.f;
      smem[ST_MK+t*4+2] = mv.z?1.f:0.f; smem[ST_MK+t*4+3] = mv.w?1.f:0.f;
    }
    if (quad < 2) {
      const float* pr = rbf + ((size_t)i*NTOK + j0 + col)*16 + quad*8;
      cr00 = *(const float4*)pr;       cr01 = *(const float4*)(pr+4);
      cr10 = *(const float4*)(pr+256); cr11 = *(const float4*)(pr+260);
    }
  }

  f32x4 acc[6] = {{0,0,0,0},{0,0,0,0},{0,0,0,0},{0,0,0,0},{0,0,0,0},{0,0,0,0}};
  float biasp[3] = {0.f, 0.f, 0.f};
  const f32x4 zc = {0.f, 0.f, 0.f, 0.f};

  for (int tile = 0; tile < NTILE; ++tile) {
    const int buf = (tile & 1) * ST_SIZE;
    __syncthreads();   // staging for this tile visible; other buffer free

    // ---- issue global loads for tile+1 into regs ----
    float4 pfA, pfB, pfC, pfD; int4 pfE;
    float4 nr00, nr01, nr10, nr11;
    const bool more = (tile + 1 < NTILE);
    if (more) {
      const int j0 = (tile+1)*TJ;
      if (t < 128) pfA = *(const float4*)(f0 + (j0 + (t>>2))*16 + (t&3)*4);
      { const int q = t, jj = q/12, e = q%12;
        pfB = *(const float4*)(f1 + (j0+jj)*48 + e*4); }
      if (t < 128) { const int q = t+256, jj = q/12, e = q%12;
        pfC = *(const float4*)(f1 + (j0+jj)*48 + e*4); }
      if (t < 24) pfD = *(const float4*)(rhat + ((size_t)i*NTOK + j0)*3 + t*4);
      if (t < 8)  pfE = *(const int4*)(mask + (size_t)i*NTOK + j0 + t*4);
      if (quad < 2) {
        const float* pr = rbf + ((size_t)i*NTOK + j0 + col)*16 + quad*8;
        nr00 = *(const float4*)pr;       nr01 = *(const float4*)(pr+4);
        nr10 = *(const float4*)(pr+256); nr11 = *(const float4*)(pr+260);
      }
    }

    // ---- lhs in-lane: m = base_mt*16..+nmt*16 (row col), j = quad*8+e ----
    bf16x8 Lh[3], Ll[3];
    {
      #pragma unroll
      for (int lmt = 0; lmt < 3; ++lmt) {
        if (lmt >= nmt) break;
        float vals[8]; float bs = 0.f;
        #pragma unroll
        for (int e = 0; e < 8; ++e) {
          const int j = quad*8 + e;
          const float mk = smem[buf + ST_MK + j];
          float v;
          if (w == 0) {
            v = mk * smem[buf + ST_F0 + F0IDX(j, col)];
          } else if (w == 1) {
            const int c3 = col*3;
            v = mk * (smem[buf+ST_RH+j*3+0]*smem[buf+ST_F1+F1IDX(j,c3+0)]
                    + smem[buf+ST_RH+j*3+1]*smem[buf+ST_F1+F1IDX(j,c3+1)]
                    + smem[buf+ST_RH+j*3+2]*smem[buf+ST_F1+F1IDX(j,c3+2)]);
          } else if (w == 2) {
            v = mk * smem[buf + ST_F0 + F0IDX(j, fI[lmt])] * smem[buf + ST_RH + j*3 + xI[lmt]];
          } else {
            v = mk * smem[buf + ST_F1 + F1IDX(j, lmt*16 + col)];
          }
          vals[e] = v; bs += v;
        }
        biasp[lmt] += bs;
        short hh[8], ll[8];
        #pragma unroll
        for (int e = 0; e < 8; ++e) { HL s = splitbf(vals[e]); hh[e] = s.hi; ll[e] = s.lo; }
        Lh[lmt] = frag4(pk(hh[0],hh[1]), pk(hh[2],hh[3]), pk(hh[4],hh[5]), pk(hh[6],hh[7]));
        Ll[lmt] = frag4(pk(ll[0],ll[1]), pk(ll[2],ll[3]), pk(ll[4],ll[5]), pk(ll[6],ll[7]));
      }
    }

    // ---- phase A: 3xBF16 MFMA, silu, split -> packed H dwords in regs ----
    int dwH[2][2][2], dwL[2][2][2];   // [hnl][jh][pos]
    {
      bf16x8 a0h={0,0,0,0,0,0,0,0}, a0l={0,0,0,0,0,0,0,0};
      bf16x8 a1h={0,0,0,0,0,0,0,0}, a1l={0,0,0,0,0,0,0,0};
      if (quad < 2) {
        const float v0[8] = {cr00.x,cr00.y,cr00.z,cr00.w,cr01.x,cr01.y,cr01.z,cr01.w};
        const float v1[8] = {cr10.x,cr10.y,cr10.z,cr10.w,cr11.x,cr11.y,cr11.z,cr11.w};
        #pragma unroll
        for (int e = 0; e < 8; ++e) {
          HL s0 = splitbf(v0[e]); a0h[e] = s0.hi; a0l[e] = s0.lo;
          HL s1 = splitbf(v1[e]); a1h[e] = s1.hi; a1l[e] = s1.lo;
        }
      }
      f32x4 d[2][2];  // [hnl][jh]
      d[0][0] = __builtin_amdgcn_mfma_f32_16x16x32_bf16(a0l, bw0h, zc, 0,0,0);
      d[0][0] = __builtin_amdgcn_mfma_f32_16x16x32_bf16(a0h, bw0l, d[0][0], 0,0,0);
      d[0][0] = __builtin_amdgcn_mfma_f32_16x16x32_bf16(a0h, bw0h, d[0][0], 0,0,0);
      d[1][0] = __builtin_amdgcn_mfma_f32_16x16x32_bf16(a0l, bw1h, zc, 0,0,0);
      d[1][0] = __builtin_amdgcn_mfma_f32_16x16x32_bf16(a0h, bw1l, d[1][0], 0,0,0);
      d[1][0] = __builtin_amdgcn_mfma_f32_16x16x32_bf16(a0h, bw1h, d[1][0], 0,0,0);
      d[0][1] = __builtin_amdgcn_mfma_f32_16x16x32_bf16(a1l, bw0h, zc, 0,0,0);
      d[0][1] = __builtin_amdgcn_mfma_f32_16x16x32_bf16(a1h, bw0l, d[0][1], 0,0,0);
      d[0][1] = __builtin_amdgcn_mfma_f32_16x16x32_bf16(a1h, bw0h, d[0][1], 0,0,0);
      d[1][1] = __builtin_amdgcn_mfma_f32_16x16x32_bf16(a1l, bw1h, zc, 0,0,0);
      d[1][1] = __builtin_amdgcn_mfma_f32_16x16x32_bf16(a1h, bw1l, d[1][1], 0,0,0);
      d[1][1] = __builtin_amdgcn_mfma_f32_16x16x32_bf16(a1h, bw1h, d[1][1], 0,0,0);
      #pragma unroll
      for (int hnl = 0; hnl < 2; ++hnl) {
        const float bav = hnl ? ba1v : ba0v;
        #pragma unroll
        for (int jh = 0; jh < 2; ++jh) {
          short sh[4], sl[4];
          #pragma unroll
          for (int r = 0; r < 4; ++r) {
            float p = d[hnl][jh][r] + bav;
            float s = p / (1.f + __expf(-p));
            HL e2 = splitbf(s); sh[r] = e2.hi; sl[r] = e2.lo;
          }
          dwH[hnl][jh][0] = pk(sh[0], sh[1]); dwH[hnl][jh][1] = pk(sh[2], sh[3]);
          dwL[hnl][jh][0] = pk(sl[0], sl[1]); dwL[hnl][jh][1] = pk(sl[2], sl[3]);
        }
      }
    }

    // ---- bpermute H -> B-frags (k=j layout), then phase B MFMAs ----
    #pragma unroll
    for (int hnl = 0; hnl < 2; ++hnl) {
      int A0h0 = __builtin_amdgcn_ds_bpermute(srcA, dwH[hnl][0][0]);
      int A1h0 = __builtin_amdgcn_ds_bpermute(srcA, dwH[hnl][0][1]);
      int B0h0 = __builtin_amdgcn_ds_bpermute(srcB, dwH[hnl][0][0]);
      int B1h0 = __builtin_amdgcn_ds_bpermute(srcB, dwH[hnl][0][1]);
      int A0h1 = __builtin_amdgcn_ds_bpermute(srcA, dwH[hnl][1][0]);
      int A1h1 = __builtin_amdgcn_ds_bpermute(srcA, dwH[hnl][1][1]);
      int B0h1 = __builtin_amdgcn_ds_bpermute(srcB, dwH[hnl][1][0]);
      int B1h1 = __builtin_amdgcn_ds_bpermute(srcB, dwH[hnl][1][1]);
      bf16x8 Bh = frag4(jlo ? A0h0 : A0h1, jlo ? A1h0 : A1h1,
                        jlo ? B0h0 : B0h1, jlo ? B1h0 : B1h1);
      int A0l0 = __builtin_amdgcn_ds_bpermute(srcA, dwL[hnl][0][0]);
      int A1l0 = __builtin_amdgcn_ds_bpermute(srcA, dwL[hnl][0][1]);
      int B0l0 = __builtin_amdgcn_ds_bpermute(srcB, dwL[hnl][0][0]);
      int B1l0 = __builtin_amdgcn_ds_bpermute(srcB, dwL[hnl][0][1]);
      int A0l1 = __builtin_amdgcn_ds_bpermute(srcA, dwL[hnl][1][0]);
      int A1l1 = __builtin_amdgcn_ds_bpermute(srcA, dwL[hnl][1][1]);
      int B0l1 = __builtin_amdgcn_ds_bpermute(srcB, dwL[hnl][1][0]);
      int B1l1 = __builtin_amdgcn_ds_bpermute(srcB, dwL[hnl][1][1]);
      bf16x8 Bl = frag4(jlo ? A0l0 : A0l1, jlo ? A1l0 : A1l1,
                        jlo ? B0l0 : B0l1, jlo ? B1l0 : B1l1);
      #pragma unroll
      for (int lmt = 0; lmt < 3; ++lmt) {
        if (lmt >= nmt) break;
        const int a = lmt*2 + hnl;
        acc[a] = __builtin_amdgcn_mfma_f32_16x16x32_bf16(Ll[lmt], Bh, acc[a], 0,0,0);
        acc[a] = __builtin_amdgcn_mfma_f32_16x16x32_bf16(Lh[lmt], Bl, acc[a], 0,0,0);
        acc[a] = __builtin_amdgcn_mfma_f32_16x16x32_bf16(Lh[lmt], Bh, acc[a], 0,0,0);
      }
    }

    // ---- store staged regs for tile+1 into other buffer ----
    if (more) {
      const int nb = ((tile+1) & 1) * ST_SIZE;
      if (t < 128) { const int jj = t>>2, e = t&3;
        *(float4*)&smem[nb + ST_F0 + F0IDX(jj, e*4)] = pfA; }
      { const int q = t, jj = q/12, e = q%12;
        if (q < 384) *(float4*)&smem[nb + ST_F1 + F1IDX(jj, e*4)] = pfB; }
      if (t < 128) { const int q = t+256, jj = q/12, e = q%12;
        *(float4*)&smem[nb + ST_F1 + F1IDX(jj, e*4)] = pfC; }
      if (t < 24) *(float4*)&smem[nb + ST_RH + t*4] = pfD;
      if (t < 8) {
        smem[nb+ST_MK+t*4+0] = pfE.x?1.f:0.f; smem[nb+ST_MK+t*4+1] = pfE.y?1.f:0.f;
        smem[nb+ST_MK+t*4+2] = pfE.z?1.f:0.f; smem[nb+ST_MK+t*4+3] = pfE.w?1.f:0.f;
      }
      cr00 = nr00; cr01 = nr01; cr10 = nr10; cr11 = nr11;
    }
  }

  // ---- epilogue: dump ACC (overlay on staging) + bias, contract, LN ----
  __syncthreads();   // all staging reads done; overlay safe
  #pragma unroll
  for (int lmt = 0; lmt < 3; ++lmt) {
    if (lmt >= nmt) break;
    const int mt = base_mt + lmt;
    #pragma unroll
    for (int hnl = 0; hnl < 2; ++hnl)
      #pragma unroll
      for (int r = 0; r < 4; ++r)
        ACCf[(mt*16 + quad*4 + r)*33 + hnl*16 + col] = acc[lmt*2 + hnl][r];
    biasb[(mt*16 + col)*4 + quad] = biasp[lmt];
  }
  __syncthreads();

  float* m00s = smem + OFF_EPI;        // 16
  float* m10s = m00s + 16;             // 16
  float* p01s = m10s + 16;             // 48
  float* p11s = p01s + 48;             // 48
  float* rawb = p11s + 48;             // 48
  float* nrms = rawb + 48;             // 16

  if (t < 16) {
    const int o = t; float s = 0.f;
    for (int d = 0; d < 16; ++d) {
      const float* wrow = w00b + (d*16 + o)*32;
      float ss = 0.f;
      #pragma unroll
      for (int h = 0; h < 32; ++h) ss += wrow[h] * ACCf[d*33 + h];
      const float bv = biasb[d*4]+biasb[d*4+1]+biasb[d*4+2]+biasb[d*4+3];
      s += ss + b00b[d*16 + o] * bv;
    }
    m00s[o] = s;
  } else if (t < 32) {
    const int o = t - 16; float s = 0.f;
    for (int c = 0; c < 16; ++c) {
      const int m = 16 + c;
      const float* wrow = w10b + (c*16 + o)*32;
      float ss = 0.f;
      #pragma unroll
      for (int h = 0; h < 32; ++h) ss += wrow[h] * ACCf[m*33 + h];
      const float bv = biasb[m*4]+biasb[m*4+1]+biasb[m*4+2]+biasb[m*4+3];
      s += ss + b10b[c*16 + o] * bv;
    }
    m10s[o] = s;
  } else if (t < 80) {
    const int idx = t - 32, g = idx/3, x = idx%3; float s = 0.f;
    for (int f = 0; f < 16; ++f) {
      const int m = 32 + f*3 + x;
      const float* wrow = w01b + (f*16 + g)*32;
      float ss = 0.f;
      #pragma unroll
      for (int h = 0; h < 32; ++h) ss += wrow[h] * ACCf[m*33 + h];
      const float bv = biasb[m*4]+biasb[m*4+1]+biasb[m*4+2]+biasb[m*4+3];
      s += ss + b01b[f*16 + g] * bv;
    }
    p01s[idx] = s;
  } else if (t < 128) {
    const int idx = t - 80, g = idx/3, x = idx%3; float s = 0.f;
    for (int k = 0; k < 16; ++k) {
      const int m = 80 + k*3 + x;
      const float* wrow = w11b + (k*16 + g)*32;
      float ss = 0.f;
      #pragma unroll
      for (int h = 0; h < 32; ++h) ss += wrow[h] * ACCf[m*33 + h];
      const float bv = biasb[m*4]+biasb[m*4+1]+biasb[m*4+2]+biasb[m*4+3];
      s += ss + b11b[k*16 + g] * bv;
    }
    p11s[idx] = s;
  }
  __syncthreads();

  if (t < 16) {
    float v = m00s[t] + m10s[t];
    float mu = 0.f;
    #pragma unroll
    for (int k = 0; k < 16; ++k) mu += m00s[k] + m10s[k];
    mu *= (1.f/16.f);
    float var = 0.f;
    #pragma unroll
    for (int k = 0; k < 16; ++k) { float d = m00s[k] + m10s[k] - mu; var += d*d; }
    var *= (1.f/16.f);
    out[(size_t)i*16 + t] = (v - mu) * rsqrtf(var + EPSF) * g0[t] + be0[t];
    float r0v = p01s[t*3+0] + p11s[t*3+0];
    float r1v = p01s[t*3+1] + p11s[t*3+1];
    float r2v = p01s[t*3+2] + p11s[t*3+2];
    rawb[t*3+0] = r0v; rawb[t*3+1] = r1v; rawb[t*3+2] = r2v;
    nrms[t] = fmaxf(sqrtf(r0v*r0v + r1v*r1v + r2v*r2v), 1e-8f);
  }
  __syncthreads();
  if (t < 16) {
    float mu = 0.f;
    #pragma unroll
    for (int k = 0; k < 16; ++k) mu += nrms[k];
    mu *= (1.f/16.f);
    float var = 0.f;
    #pragma unroll
    for (int k = 0; k < 16; ++k) { float d = nrms[k] - mu; var += d*d; }
    var *= (1.f/16.f);
    const float ln = (nrms[t] - mu) * rsqrtf(var + EPSF) * g1[t] + be1[t];
    const float scale = ln / nrms[t];
    const size_t base = (size_t)NTOK*16 + (size_t)i*48 + t*3;
    out[base+0] = rawb[t*3+0] * scale;
    out[base+1] = rawb[t*3+1] * scale;
    out[base+2] = rawb[t*3+2] * scale;
  }
}

extern "C" void kernel_launch(void* const* d_in, const int* in_sizes, int n_in,
                              void* d_out, int out_size, void* d_ws, size_t ws_size,
                              hipStream_t stream) {
  int idx_f0 = -1, idx_f1 = -1, idx_rbf = -1, idx_rhat = -1, idx_mask = -1;
  int wa_i[4], ba_i[4], wb_i[4], bb_i[4], g_i[4];
  int nwa = 0, nba = 0, nwb = 0, nbb = 0, ng = 0;
  for (int k = 0; k < n_in; ++k) {
    const int s = in_sizes[k];
    if      (s == 4194304) idx_rbf  = k;
    else if (s == 786432)  idx_rhat = k;
    else if (s == 262144)  idx_mask = k;
    else if (s == 24576)   idx_f1   = k;
    else if (s == 8192)    { if (idx_f0 < 0) idx_f0 = k; else if (nwb < 4) wb_i[nwb++] = k; }
    else if (s == 512)     { if (nwa < 4) wa_i[nwa++] = k; }
    else if (s == 32)      { if (nba < 4) ba_i[nba++] = k; }
    else if (s == 256)     { if (nbb < 4) bb_i[nbb++] = k; }
    else if (s == 16)      { if (ng  < 4) g_i[ng++]  = k; }
  }
  const bool ok = idx_f0 >= 0 && idx_f1 >= 0 && idx_rbf >= 0 && idx_rhat >= 0 &&
                  idx_mask >= 0 && nwa == 4 && nba == 4 && nwb == 4 && nbb == 4 && ng == 4;
  if (!ok) {
    idx_f0 = 1; idx_f1 = 2; idx_rbf = 3; idx_rhat = 4; idx_mask = 5;
    for (int q = 0; q < 4; ++q) {
      wa_i[q] = 6 + q*4; ba_i[q] = 7 + q*4; wb_i[q] = 8 + q*4; bb_i[q] = 9 + q*4;
      g_i[q] = 22 + q;
    }
  }
  tfn_mono<<<512, 256, 0, stream>>>(
      (const float*)d_in[idx_f0],  (const float*)d_in[idx_f1],
      (const float*)d_in[idx_rbf], (const float*)d_in[idx_rhat],
      (const int*)d_in[idx_mask],
      (const float*)d_in[wa_i[0]], (const float*)d_in[ba_i[0]],
      (const float*)d_in[wb_i[0]], (const float*)d_in[bb_i[0]],
      (const float*)d_in[wa_i[1]], (const float*)d_in[ba_i[1]],
      (const float*)d_in[wb_i[1]], (const float*)d_in[bb_i[1]],
      (const float*)d_in[wa_i[2]], (const float*)d_in[ba_i[2]],
      (const float*)d_in[wb_i[2]], (const float*)d_in[bb_i[2]],
      (const float*)d_in[wa_i[3]], (const float*)d_in[ba_i[3]],
      (const float*)d_in[wb_i[3]], (const float*)d_in[bb_i[3]],
      (const float*)d_in[g_i[0]], (const float*)d_in[g_i[1]],
      (const float*)d_in[g_i[2]], (const float*)d_in[g_i[3]],
      (float*)d_out);
}